// Round 4
// baseline (205.241 us; speedup 1.0000x reference)
//
#include <hip/hip_runtime.h>
#include <hip/hip_cooperative_groups.h>
#include <math.h>

namespace cg = cooperative_groups;

#define BB 2048
#define CC 1000
#define DD 64
#define NBLK 512          // 2 blocks/CU -> cooperative-resident
#define ROWS 16           // b-rows per score tile

constexpr float EPS_STATS = 1e-5f;
constexpr float EPS_PREC  = 1e-6f;
constexpr float TSUM = (float)BB + (float)CC * EPS_STATS;  // counts.sum()

// One cooperative kernel: zero -> accum(atomics) -> stats -> score.
// 512 blocks x 256 threads; phases separated by grid.sync().
__global__ void __launch_bounds__(256, 2)
k_fused(const float* __restrict__ z, const int* __restrict__ y,
        float* __restrict__ sums,        // C*D
        float* __restrict__ sumsq,       // C*D (contiguous after sums)
        int*   __restrict__ ncnt,        // C   (contiguous after sumsq)
        float* __restrict__ pooledPart,  // 250*D
        float* __restrict__ meanT,       // D*C
        float* __restrict__ logpr,       // C
        float* __restrict__ out)         // B*C
{
    __shared__ float part[4][DD];   // phase 2
    __shared__ float zs[ROWS][DD];  // phase 3
    __shared__ float ps[DD];
    __shared__ float red[4][DD];
    __shared__ float sr[ROWS];

    cg::grid_group grid = cg::this_grid();
    const int tid = threadIdx.x;
    const int bid = blockIdx.x;
    const int idx = bid * 256 + tid;       // 0 .. 131071

    // ---- Phase 0: zero sums/sumsq/ncnt (129000 words; ws is poisoned) ----
    if (idx < 2 * CC * DD + CC) ((float*)sums)[idx] = 0.f;   // int 0 == 0.f bits
    grid.sync();

    // ---- Phase 1: atomic accumulation (idx == b*64 + d exactly) ----
    {
        int b = idx >> 6, d = idx & 63;
        int c = y[b];
        float v = z[idx];                  // coalesced
        atomicAdd(&sums[c * DD + d], v);
        atomicAdd(&sumsq[c * DD + d], v * v);
        if (d == 0) atomicAdd(&ncnt[c], 1);
    }
    grid.sync();

    // ---- Phase 2: blocks 0..249 -> means (transposed), log-prior, pooled partials
    if (bid < 250) {
        int c = idx >> 6;                  // 4 classes per block
        int d = idx & 63;
        float nn = (float)ncnt[c];
        float ce = nn + EPS_STATS;
        float s = sums[idx];               // coalesced
        float q = sumsq[idx];
        float m = s / ce;
        meanT[d * CC + c] = m;             // scattered, L2-resident
        if (d == 0) logpr[c] = logf(ce / TSUM);
        // class contribution to pooled cov at dim d: q - 2ms + n m^2
        part[tid >> 6][d] = fmaf(nn * m, m, fmaf(-2.f * m, s, q));
        __syncthreads();
        if (tid < DD)
            pooledPart[bid * DD + tid] =
                part[0][tid] + part[1][tid] + part[2][tid] + part[3][tid];
    }
    grid.sync();

    // ---- Phase 3: scoring. bid -> (btile 0..127, ctile 0..3) ----
    {
        int btile = bid >> 2;
        int ctile = bid & 3;
        int d = tid & 63, chunk = tid >> 6;

        // precision: redundant per-block reduction of pooledPart (L2-cheap)
        float acc = 0.f;
        for (int p = chunk; p < 250; p += 4) acc += pooledPart[p * DD + d];
        red[chunk][d] = acc;

        int b0 = btile * ROWS;
        #pragma unroll
        for (int i = 0; i < (ROWS * DD) / 256; ++i) {
            int ii = tid + i * 256;
            zs[ii >> 6][ii & 63] = z[b0 * DD + ii];
        }
        __syncthreads();
        if (tid < DD) {
            float pooled = (red[0][tid] + red[1][tid] + red[2][tid] + red[3][tid]) / TSUM
                           + EPS_STATS;
            ps[tid] = 1.0f / fmaxf(pooled, EPS_PREC);
        }
        __syncthreads();
        // S_r = sum_d p_d z_rd^2 (shared across classes)
        if (tid < ROWS) {
            float a = 0.f;
            #pragma unroll 16
            for (int dd2 = 0; dd2 < DD; ++dd2) {
                float v = zs[tid][dd2];
                a = fmaf(ps[dd2] * v, v, a);
            }
            sr[tid] = a;
        }
        __syncthreads();

        int c  = ctile * 256 + tid;
        int cc = (c < CC) ? c : (CC - 1);
        float logp = logpr[cc];

        float dot[ROWS];
        #pragma unroll
        for (int r = 0; r < ROWS; ++r) dot[r] = 0.f;
        float K = 0.f;

        #pragma unroll 8
        for (int dd2 = 0; dd2 < DD; ++dd2) {
            float m = meanT[dd2 * CC + cc];   // coalesced across lanes
            float w = ps[dd2] * m;
            K = fmaf(w, m, K);                // sum_d p m^2
            #pragma unroll
            for (int r = 0; r < ROWS; ++r)
                dot[r] = fmaf(w, zs[r][dd2], dot[r]);   // 1 LDS + 1 FMA
        }

        if (c < CC) {
            #pragma unroll
            for (int r = 0; r < ROWS; ++r) {
                float m2 = sr[r] - 2.f * dot[r] + K;
                out[(size_t)(b0 + r) * CC + c] = fmaf(-0.5f, m2, logp);
            }
        }
    }
}

extern "C" void kernel_launch(void* const* d_in, const int* in_sizes, int n_in,
                              void* d_out, int out_size, void* d_ws, size_t ws_size,
                              hipStream_t stream) {
    const float* z = (const float*)d_in[0];
    const int*   y = (const int*)d_in[1];
    float* out = (float*)d_out;

    // ws layout: sums | sumsq | ncnt must be contiguous (phase-0 zeroing)
    float* sums       = (float*)d_ws;            // 64000
    float* sumsq      = sums + CC * DD;          // 64000
    int*   ncnt       = (int*)(sumsq + CC * DD); // 1000
    float* pooledPart = (float*)(ncnt + CC);     // 16000
    float* meanT      = pooledPart + 250 * DD;   // 64000
    float* logpr      = meanT + DD * CC;         // 1000

    void* args[] = {(void*)&z, (void*)&y, (void*)&sums, (void*)&sumsq,
                    (void*)&ncnt, (void*)&pooledPart, (void*)&meanT,
                    (void*)&logpr, (void*)&out};
    hipLaunchCooperativeKernel((const void*)k_fused, dim3(NBLK), dim3(256),
                               args, 0, stream);
}

// Round 5
// 43.900 us; speedup vs baseline: 4.6752x; 4.6752x over previous
//
#include <hip/hip_runtime.h>
#include <math.h>

#define BB 2048
#define CC 1000
#define DD 64
constexpr float EPS_STATS = 1e-5f;
constexpr float EPS_PREC  = 1e-6f;
constexpr float TSUM = (float)BB + (float)CC * EPS_STATS;  // counts.sum()

// ws word counts
#define N_ZERO (CC * DD + CC)        // sums + ncnt = 65000 words

// --- K0: zero sums+ncnt; blocks 0..63 also compute T2part[64][64] (no atomics).
// T2_d = sum_b z_bd^2 ; block bid covers rows [bid*32, bid*32+32).
__global__ void __launch_bounds__(256)
k_zero_t2(const float* __restrict__ z, unsigned* __restrict__ zeroBase,
          float* __restrict__ T2part) {
    __shared__ float part[4][DD];
    int tid = threadIdx.x, bid = blockIdx.x;
    int w = bid * 256 + tid;
    if (w < N_ZERO) zeroBase[w] = 0u;
    if (bid < 64) {
        int d = tid & 63, grp = tid >> 6;
        int r0 = bid * 32 + grp * 8;
        float a = 0.f;
        #pragma unroll
        for (int r = 0; r < 8; ++r) {
            float v = z[(r0 + r) * DD + d];    // coalesced
            a = fmaf(v, v, a);
        }
        part[grp][d] = a;
        __syncthreads();
        if (tid < DD)
            T2part[bid * DD + tid] =
                part[0][tid] + part[1][tid] + part[2][tid] + part[3][tid];
    }
}

// --- K1: atomic accumulation of per-class sums + counts (no sumsq).
// idx = b*64+d; a wave covers one row -> class uniform per wave, contiguous 256B atomics.
__global__ void __launch_bounds__(256)
k_accum(const float* __restrict__ z, const int* __restrict__ y,
        float* __restrict__ sums, int* __restrict__ ncnt) {
    int idx = blockIdx.x * 256 + threadIdx.x;   // [0, B*D)
    int b = idx >> 6, d = idx & 63;
    int c = y[b];
    atomicAdd(&sums[c * DD + d], z[idx]);
    if (d == 0) atomicAdd(&ncnt[c], 1);
}

// --- K2: per-class finalize: meanT (transposed), logpr, corrPart.
// corr term of class c at dim d: s^2 * (n+2e)/(n+e)^2   (= 2ms - n m^2 exactly)
__global__ void __launch_bounds__(256)
k_stats(const float* __restrict__ sums, const int* __restrict__ ncnt,
        float* __restrict__ meanT, float* __restrict__ logpr,
        float* __restrict__ corrPart) {
    __shared__ float part[4][DD];
    int tid = threadIdx.x, bid = blockIdx.x;
    int idx = bid * 256 + tid;          // [0, C*D)
    int c = idx >> 6, d = idx & 63;
    float s  = sums[idx];               // coalesced
    float nn = (float)ncnt[c];
    float ce = nn + EPS_STATS;
    float inv = 1.0f / ce;
    float m = s * inv;
    meanT[d * CC + c] = m;              // transpose write, tiny
    if (d == 0) logpr[c] = logf(ce / TSUM);
    part[tid >> 6][d] = s * s * (nn + 2.f * EPS_STATS) * inv * inv;
    __syncthreads();
    if (tid < DD)
        corrPart[bid * DD + tid] =
            part[0][tid] + part[1][tid] + part[2][tid] + part[3][tid];
}

// --- K3: scoring. grid (B/ROWS, 4), 256 thr = 256 classes.
// Inline prec reduce (T2part - corrPart), then m2 = S_r - 2*dot + K_c.
#define ROWS 8
__global__ void __launch_bounds__(256)
k_score(const float* __restrict__ z, const float* __restrict__ meanT,
        const float* __restrict__ logpr, const float* __restrict__ T2part,
        const float* __restrict__ corrPart, float* __restrict__ out) {
    __shared__ float zs[ROWS][DD];
    __shared__ float ps[DD];
    __shared__ float red[4][DD];
    __shared__ float sr[ROWS];
    int tid = threadIdx.x;
    int d = tid & 63, chunk = tid >> 6;

    // precision: redundant per-block reduction (coalesced L2 reads)
    float acc = 0.f;
    for (int t = chunk; t < 64; t += 4) acc += T2part[t * DD + d];
    for (int p = chunk; p < 250; p += 4) acc -= corrPart[p * DD + d];
    red[chunk][d] = acc;

    int b0 = blockIdx.x * ROWS;
    #pragma unroll
    for (int i = 0; i < (ROWS * DD) / 256; ++i) {
        int ii = tid + i * 256;
        zs[ii >> 6][ii & 63] = z[b0 * DD + ii];
    }
    __syncthreads();
    if (tid < DD) {
        float pooled = (red[0][tid] + red[1][tid] + red[2][tid] + red[3][tid]) / TSUM
                       + EPS_STATS;
        ps[tid] = 1.0f / fmaxf(pooled, EPS_PREC);
    }
    __syncthreads();
    if (tid < ROWS) {          // S_r = sum_d p_d z_rd^2
        float a = 0.f;
        #pragma unroll 16
        for (int dd = 0; dd < DD; ++dd) {
            float v = zs[tid][dd];
            a = fmaf(ps[dd] * v, v, a);
        }
        sr[tid] = a;
    }
    __syncthreads();

    int c  = blockIdx.y * 256 + tid;
    int cc = (c < CC) ? c : (CC - 1);
    float logp = logpr[cc];

    float dot[ROWS];
    #pragma unroll
    for (int r = 0; r < ROWS; ++r) dot[r] = 0.f;
    float K = 0.f;

    #pragma unroll 8
    for (int dd = 0; dd < DD; ++dd) {
        float m = meanT[dd * CC + cc];   // coalesced across lanes (L2-resident)
        float w = ps[dd] * m;
        K = fmaf(w, m, K);
        #pragma unroll
        for (int r = 0; r < ROWS; ++r)
            dot[r] = fmaf(w, zs[r][dd], dot[r]);
    }

    if (c < CC) {
        #pragma unroll
        for (int r = 0; r < ROWS; ++r) {
            float m2 = sr[r] - 2.f * dot[r] + K;
            out[(size_t)(b0 + r) * CC + c] = fmaf(-0.5f, m2, logp);
        }
    }
}

extern "C" void kernel_launch(void* const* d_in, const int* in_sizes, int n_in,
                              void* d_out, int out_size, void* d_ws, size_t ws_size,
                              hipStream_t stream) {
    const float* z = (const float*)d_in[0];
    const int*   y = (const int*)d_in[1];
    float* out = (float*)d_out;

    float* sums     = (float*)d_ws;             // 64000
    int*   ncnt     = (int*)(sums + CC * DD);   // 1000 (contiguous: zeroed with sums)
    float* T2part   = (float*)(ncnt + CC);      // 64*64 = 4096
    float* corrPart = T2part + 64 * DD;         // 250*64 = 16000
    float* meanT    = corrPart + 250 * DD;      // 64000
    float* logpr    = meanT + DD * CC;          // 1000

    k_zero_t2<<<256, 256, 0, stream>>>(z, (unsigned*)d_ws, T2part);
    k_accum  <<<(BB * DD) / 256, 256, 0, stream>>>(z, y, sums, ncnt);
    k_stats  <<<250, 256, 0, stream>>>(sums, ncnt, meanT, logpr, corrPart);
    dim3 grid(BB / ROWS, 4);
    k_score  <<<grid, 256, 0, stream>>>(z, meanT, logpr, T2part, corrPart, out);
}

// Round 6
// 38.059 us; speedup vs baseline: 5.3927x; 1.1535x over previous
//
#include <hip/hip_runtime.h>
#include <math.h>

#define BB 2048
#define CC 1000
#define DD 64
constexpr float EPS_STATS = 1e-5f;
constexpr float EPS_PREC  = 1e-6f;
constexpr float TSUM = (float)BB + (float)CC * EPS_STATS;  // counts.sum()

// --- K_A: single stats kernel, no atomics (global), no zeroing.
// Blocks 0..249: 4 classes each. Parallel y-scan (8 checks/thread) -> match
// list -> per-wave gather of ~2 z-rows -> meanT, logpr, corrPart.
// Blocks 250..313: T2part[t][d] = partial sum of z^2 over 32 rows.
__global__ void __launch_bounds__(256)
k_stats(const float* __restrict__ z, const int* __restrict__ y,
        float* __restrict__ meanT, float* __restrict__ logpr,
        float* __restrict__ corrPart, float* __restrict__ T2part) {
    int tid = threadIdx.x, bid = blockIdx.x;
    if (bid < 250) {
        __shared__ int ys[BB];       // 8 KB
        __shared__ int mlist[BB];    // 8 KB (pathological-y safe)
        __shared__ int mcnt;
        __shared__ float part[4][DD];
        if (tid == 0) mcnt = 0;
        #pragma unroll
        for (int i = 0; i < BB / 256; ++i) ys[tid + i * 256] = y[tid + i * 256];
        __syncthreads();
        int cbase = bid * 4;
        #pragma unroll
        for (int i = 0; i < BB / 256; ++i) {
            int b = tid + i * 256;
            int cl = ys[b] - cbase;
            if ((unsigned)cl < 4u) {
                int p = atomicAdd(&mcnt, 1);      // LDS atomic, ~8 per block
                mlist[p] = b * 4 + cl;
            }
        }
        __syncthreads();
        int n = mcnt;
        int wave = tid >> 6, d = tid & 63;
        // wave w gathers class cbase+w; branch is wave-uniform
        float s = 0.f; int cnt = 0;
        for (int j = 0; j < n; ++j) {
            int e = mlist[j];                      // LDS broadcast
            if ((e & 3) == wave) {
                s += z[(e >> 2) * DD + d];         // coalesced 256B row
                ++cnt;
            }
        }
        float nn = (float)cnt;
        float ce = nn + EPS_STATS;
        float inv = 1.0f / ce;
        float m = s * inv;
        int c = cbase + wave;
        meanT[d * CC + c] = m;                     // transpose scatter, tiny
        if (d == 0) logpr[c] = logf(ce / TSUM);
        // class corr at dim d: s^2 (n+2e)/(n+e)^2  (== 2ms - n m^2 exactly)
        part[wave][d] = s * s * (nn + 2.f * EPS_STATS) * inv * inv;
        __syncthreads();
        if (tid < DD)
            corrPart[bid * DD + tid] =
                part[0][tid] + part[1][tid] + part[2][tid] + part[3][tid];
    } else {
        __shared__ float p2[4][DD];
        int tb = bid - 250;                        // 0..63
        int d = tid & 63, grp = tid >> 6;
        int r0 = tb * 32 + grp * 8;
        float a = 0.f;
        #pragma unroll
        for (int r = 0; r < 8; ++r) {
            float v = z[(r0 + r) * DD + d];        // coalesced
            a = fmaf(v, v, a);
        }
        p2[grp][d] = a;
        __syncthreads();
        if (tid < DD)
            T2part[tb * DD + tid] =
                p2[0][tid] + p2[1][tid] + p2[2][tid] + p2[3][tid];
    }
}

// --- K_B: scoring. grid (256, 2), 256 thr; thread tile = 8 rows x 2 classes.
// m2 = S_r - 2*dot + K_c ; zs read as float4 (b128 broadcast).
#define ROWS 8
__global__ void __launch_bounds__(256)
k_score(const float* __restrict__ z, const float* __restrict__ meanT,
        const float* __restrict__ logpr, const float* __restrict__ T2part,
        const float* __restrict__ corrPart, float* __restrict__ out) {
    __shared__ __align__(16) float zs[ROWS][DD];
    __shared__ __align__(16) float ps[DD];
    __shared__ float red[4][DD];
    __shared__ float sr[ROWS];
    int tid = threadIdx.x;
    int d = tid & 63, chunk = tid >> 6;

    // precision: per-block redundant reduce (coalesced L2, 314 rows of 64)
    float acc = 0.f;
    for (int t = chunk; t < 64; t += 4) acc += T2part[t * DD + d];
    for (int p = chunk; p < 250; p += 4) acc -= corrPart[p * DD + d];
    red[chunk][d] = acc;

    int b0 = blockIdx.x * ROWS;
    #pragma unroll
    for (int i = 0; i < (ROWS * DD) / 256; ++i) {
        int ii = tid + i * 256;
        zs[ii >> 6][ii & 63] = z[b0 * DD + ii];
    }
    __syncthreads();
    if (tid < DD) {
        float pooled = (red[0][tid] + red[1][tid] + red[2][tid] + red[3][tid]) / TSUM
                       + EPS_STATS;
        ps[tid] = 1.0f / fmaxf(pooled, EPS_PREC);
    }
    __syncthreads();
    if (tid < ROWS) {          // S_r = sum_d p_d z_rd^2
        float a = 0.f;
        #pragma unroll 16
        for (int dd = 0; dd < DD; ++dd) {
            float v = zs[tid][dd];
            a = fmaf(ps[dd] * v, v, a);
        }
        sr[tid] = a;
    }
    __syncthreads();

    int c1 = blockIdx.y * 512 + tid;      // always < 1000 (max 767)
    int c2 = c1 + 256;                    // may exceed 999 when blockIdx.y==1
    int c2c = (c2 < CC) ? c2 : (CC - 1);
    float lp1 = logpr[c1], lp2 = logpr[c2c];

    float dot1[ROWS], dot2[ROWS];
    #pragma unroll
    for (int r = 0; r < ROWS; ++r) { dot1[r] = 0.f; dot2[r] = 0.f; }
    float K1 = 0.f, K2 = 0.f;

    #pragma unroll 4
    for (int q = 0; q < DD / 4; ++q) {
        float4 pq = *reinterpret_cast<const float4*>(&ps[q * 4]);  // b128 broadcast
        float w1[4], w2[4];
        #pragma unroll
        for (int k = 0; k < 4; ++k) {
            int dd = q * 4 + k;
            float pk = (&pq.x)[k];
            float m1 = meanT[dd * CC + c1];    // coalesced across lanes
            float m2 = meanT[dd * CC + c2c];
            w1[k] = pk * m1;  K1 = fmaf(w1[k], m1, K1);
            w2[k] = pk * m2;  K2 = fmaf(w2[k], m2, K2);
        }
        #pragma unroll
        for (int r = 0; r < ROWS; ++r) {
            float4 zq = *reinterpret_cast<const float4*>(&zs[r][q * 4]);  // b128 broadcast
            dot1[r] = fmaf(w1[0], zq.x, dot1[r]);
            dot1[r] = fmaf(w1[1], zq.y, dot1[r]);
            dot1[r] = fmaf(w1[2], zq.z, dot1[r]);
            dot1[r] = fmaf(w1[3], zq.w, dot1[r]);
            dot2[r] = fmaf(w2[0], zq.x, dot2[r]);
            dot2[r] = fmaf(w2[1], zq.y, dot2[r]);
            dot2[r] = fmaf(w2[2], zq.z, dot2[r]);
            dot2[r] = fmaf(w2[3], zq.w, dot2[r]);
        }
    }

    #pragma unroll
    for (int r = 0; r < ROWS; ++r) {
        float base = sr[r];
        size_t row = (size_t)(b0 + r) * CC;
        out[row + c1] = fmaf(-0.5f, base - 2.f * dot1[r] + K1, lp1);
        if (c2 < CC)
            out[row + c2] = fmaf(-0.5f, base - 2.f * dot2[r] + K2, lp2);
    }
}

extern "C" void kernel_launch(void* const* d_in, const int* in_sizes, int n_in,
                              void* d_out, int out_size, void* d_ws, size_t ws_size,
                              hipStream_t stream) {
    const float* z = (const float*)d_in[0];
    const int*   y = (const int*)d_in[1];
    float* out = (float*)d_out;

    // ws: all arrays written every call before any read; no zeroing needed.
    float* meanT    = (float*)d_ws;            // 64000
    float* logpr    = meanT + DD * CC;         // 1000
    float* corrPart = logpr + CC;              // 250*64 = 16000
    float* T2part   = corrPart + 250 * DD;     // 64*64  =  4096

    k_stats<<<314, 256, 0, stream>>>(z, y, meanT, logpr, corrPart, T2part);
    dim3 grid(BB / ROWS, 2);
    k_score<<<grid, 256, 0, stream>>>(z, meanT, logpr, T2part, corrPart, out);
}

// Round 7
// 36.223 us; speedup vs baseline: 5.6661x; 1.0507x over previous
//
#include <hip/hip_runtime.h>
#include <hip/hip_bf16.h>
#include <math.h>

#define BB 2048
#define CC 1000
#define DD 64
constexpr float EPS_STATS = 1e-5f;
constexpr float EPS_PREC  = 1e-6f;
constexpr float TSUM = (float)BB + (float)CC * EPS_STATS;  // counts.sum()

typedef __attribute__((ext_vector_type(8))) short bf8;     // 8 bf16 (4 VGPR)
typedef __attribute__((ext_vector_type(4))) float f32x4;   // MFMA acc

__device__ inline unsigned short f2bf(float f) {           // RNE f32->bf16
    __hip_bfloat16 h = __float2bfloat16(f);
    return *reinterpret_cast<unsigned short*>(&h);
}

// --- K_A: single stats kernel, no global atomics, no zeroing.
// Blocks 0..249: 4 classes each -> mean[c][d] (class-major), logpr, corrPart.
// Blocks 250..313: T2part[t][d] = partial sum of z^2 over 32 rows.
__global__ void __launch_bounds__(256)
k_stats(const float* __restrict__ z, const int* __restrict__ y,
        float* __restrict__ mean, float* __restrict__ logpr,
        float* __restrict__ corrPart, float* __restrict__ T2part) {
    int tid = threadIdx.x, bid = blockIdx.x;
    if (bid < 250) {
        __shared__ int ys[BB];       // 8 KB
        __shared__ int mlist[BB];    // 8 KB (pathological-y safe)
        __shared__ int mcnt;
        __shared__ float part[4][DD];
        if (tid == 0) mcnt = 0;
        #pragma unroll
        for (int i = 0; i < BB / 256; ++i) ys[tid + i * 256] = y[tid + i * 256];
        __syncthreads();
        int cbase = bid * 4;
        #pragma unroll
        for (int i = 0; i < BB / 256; ++i) {
            int b = tid + i * 256;
            int cl = ys[b] - cbase;
            if ((unsigned)cl < 4u) {
                int p = atomicAdd(&mcnt, 1);      // LDS atomic, ~8 per block
                mlist[p] = b * 4 + cl;
            }
        }
        __syncthreads();
        int n = mcnt;
        int wave = tid >> 6, d = tid & 63;
        float s = 0.f; int cnt = 0;
        for (int j = 0; j < n; ++j) {
            int e = mlist[j];                      // LDS broadcast
            if ((e & 3) == wave) {                 // wave-uniform branch
                s += z[(e >> 2) * DD + d];         // coalesced 256B row
                ++cnt;
            }
        }
        float nn = (float)cnt;
        float ce = nn + EPS_STATS;
        float inv = 1.0f / ce;
        float m = s * inv;
        int c = cbase + wave;
        mean[c * DD + d] = m;                      // class-major: coalesced
        if (d == 0) logpr[c] = logf(ce / TSUM);
        // class corr at dim d: s^2 (n+2e)/(n+e)^2  (== 2ms - n m^2 exactly)
        part[wave][d] = s * s * (nn + 2.f * EPS_STATS) * inv * inv;
        __syncthreads();
        if (tid < DD)
            corrPart[bid * DD + tid] =
                part[0][tid] + part[1][tid] + part[2][tid] + part[3][tid];
    } else {
        __shared__ float p2[4][DD];
        int tb = bid - 250;                        // 0..63
        int d = tid & 63, grp = tid >> 6;
        int r0 = tb * 32 + grp * 8;
        float a = 0.f;
        #pragma unroll
        for (int r = 0; r < 8; ++r) {
            float v = z[(r0 + r) * DD + d];        // coalesced
            a = fmaf(v, v, a);
        }
        p2[grp][d] = a;
        __syncthreads();
        if (tid < DD)
            T2part[tb * DD + tid] =
                p2[0][tid] + p2[1][tid] + p2[2][tid] + p2[3][tid];
    }
}

// --- K_B: fused precision + MFMA scoring. Grid (32,16); block = 64b x 64c tile.
// out[b][c] = (logpr[c] - 0.5*K_c) + dot(w_c, z_b) - 0.5*S_b,  w = p*mean.
__global__ void __launch_bounds__(256)
k_score_mfma(const float* __restrict__ z, const float* __restrict__ mean,
             const float* __restrict__ logpr, const float* __restrict__ corrPart,
             const float* __restrict__ T2part, float* __restrict__ out) {
    __shared__ float red[4][DD];
    __shared__ float ps_s[DD];
    int tid = threadIdx.x;
    int d = tid & 63, chunk = tid >> 6;

    // precision: per-block redundant reduce of partials (coalesced L2)
    float acc0 = 0.f;
    for (int t = chunk; t < 64; t += 4) acc0 += T2part[t * DD + d];
    for (int p = chunk; p < 250; p += 4) acc0 -= corrPart[p * DD + d];
    red[chunk][d] = acc0;
    __syncthreads();
    if (tid < DD) {
        float pooled = (red[0][tid] + red[1][tid] + red[2][tid] + red[3][tid]) / TSUM
                       + EPS_STATS;
        ps_s[tid] = 1.0f / fmaxf(pooled, EPS_PREC);
    }
    __syncthreads();

    int wv = tid >> 6, l = tid & 63;
    int lr = l & 15, lg = l >> 4;          // lane-row (M/N idx), k-group
    int b0 = blockIdx.x * 64 + wv * 16;    // wave's 16 output rows
    int c0 = blockIdx.y * 64;              // block's 64 classes

    // per-lane precision slice for k = lg*8+j (kstep0) and +32 (kstep1)
    float ps0[8], ps1[8];
    #pragma unroll
    for (int j = 0; j < 8; ++j) { ps0[j] = ps_s[lg * 8 + j]; ps1[j] = ps_s[32 + lg * 8 + j]; }

    // A fragments: z row (b0+lr), fp32 load -> bf16; also S_b partial
    const float* zrow = z + (size_t)(b0 + lr) * DD;
    float zf0[8], zf1[8];
    #pragma unroll
    for (int j = 0; j < 8; ++j) zf0[j] = zrow[lg * 8 + j];
    #pragma unroll
    for (int j = 0; j < 8; ++j) zf1[j] = zrow[32 + lg * 8 + j];
    bf8 a0, a1;
    float sbp = 0.f;
    #pragma unroll
    for (int j = 0; j < 8; ++j) {
        a0[j] = (short)f2bf(zf0[j]);
        a1[j] = (short)f2bf(zf1[j]);
        sbp = fmaf(ps0[j] * zf0[j], zf0[j], sbp);
        sbp = fmaf(ps1[j] * zf1[j], zf1[j], sbp);
    }
    sbp += __shfl_xor(sbp, 16);
    sbp += __shfl_xor(sbp, 32);            // lane now holds S for row b0+lr

    f32x4 acc[4];
    float cstv[4];
    #pragma unroll
    for (int ct = 0; ct < 4; ++ct) {
        int c = c0 + ct * 16 + lr;
        int cm = (c < CC) ? c : (CC - 1);
        const float* mrow = mean + (size_t)cm * DD;
        bf8 w0, w1;
        float kc = 0.f;
        #pragma unroll
        for (int j = 0; j < 8; ++j) {
            float m0 = mrow[lg * 8 + j];
            float m1 = mrow[32 + lg * 8 + j];
            float wf0 = ps0[j] * m0, wf1 = ps1[j] * m1;
            w0[j] = (short)f2bf(wf0);
            w1[j] = (short)f2bf(wf1);
            kc = fmaf(wf0, m0, kc);
            kc = fmaf(wf1, m1, kc);
        }
        kc += __shfl_xor(kc, 16);
        kc += __shfl_xor(kc, 32);          // K_c for class cm
        cstv[ct] = fmaf(-0.5f, kc, logpr[cm]);
        f32x4 a = {0.f, 0.f, 0.f, 0.f};
        a = __builtin_amdgcn_mfma_f32_16x16x32_bf16(a0, w0, a, 0, 0, 0);
        a = __builtin_amdgcn_mfma_f32_16x16x32_bf16(a1, w1, a, 0, 0, 0);
        acc[ct] = a;
    }

    // epilogue: D row = lg*4+r, col = lr
    float sbv[4];
    #pragma unroll
    for (int r = 0; r < 4; ++r) sbv[r] = __shfl(sbp, lg * 4 + r);
    #pragma unroll
    for (int ct = 0; ct < 4; ++ct) {
        int c = c0 + ct * 16 + lr;
        if (c < CC) {
            #pragma unroll
            for (int r = 0; r < 4; ++r) {
                int b = b0 + lg * 4 + r;
                out[(size_t)b * CC + c] = acc[ct][r] + cstv[ct] - 0.5f * sbv[r];
            }
        }
    }
}

extern "C" void kernel_launch(void* const* d_in, const int* in_sizes, int n_in,
                              void* d_out, int out_size, void* d_ws, size_t ws_size,
                              hipStream_t stream) {
    const float* z = (const float*)d_in[0];
    const int*   y = (const int*)d_in[1];
    float* out = (float*)d_out;

    // ws: all arrays written every call before read; no zeroing needed.
    float* mean     = (float*)d_ws;            // 64000 (class-major [c][d])
    float* logpr    = mean + DD * CC;          // 1000
    float* corrPart = logpr + CC;              // 250*64 = 16000
    float* T2part   = corrPart + 250 * DD;     // 64*64  =  4096

    k_stats<<<314, 256, 0, stream>>>(z, y, mean, logpr, corrPart, T2part);
    dim3 grid(BB / 64, (CC + 63) / 64);        // 32 x 16
    k_score_mfma<<<grid, 256, 0, stream>>>(z, mean, logpr, corrPart, T2part, out);
}

// Round 8
// 23.124 us; speedup vs baseline: 8.8756x; 1.5665x over previous
//
#include <hip/hip_runtime.h>
#include <hip/hip_bf16.h>
#include <math.h>

#define BB 2048
#define CC 1000
#define DD 64
constexpr float EPS_STATS = 1e-5f;
constexpr float EPS_PREC  = 1e-6f;
constexpr float TSUM = (float)BB + (float)CC * EPS_STATS;  // counts.sum()

typedef __attribute__((ext_vector_type(8))) short bf8;     // 8 bf16 (4 VGPR)
typedef __attribute__((ext_vector_type(4))) float f32x4;   // MFMA acc

__device__ inline unsigned short f2bf(float f) {           // RNE f32->bf16
    __hip_bfloat16 h = __float2bfloat16(f);
    return *reinterpret_cast<unsigned short*>(&h);
}

// --- K_A: stats, fully parallel (no serial per-wave gather).
// Blocks 0..249: 4 classes each -> mean[c][d], logpr, corrPart[bid][d].
//   scan y (LDS) -> compact match list -> wave-parallel gather (4 rows/round,
//   LDS float atomics, <=4-way contention) -> finalize.
// Blocks 250..313: T2part[t][d] = partial sum of z^2 over 32 rows.
__global__ void __launch_bounds__(256)
k_stats(const float* __restrict__ z, const int* __restrict__ y,
        float* __restrict__ mean, float* __restrict__ logpr,
        float* __restrict__ corrPart, float* __restrict__ T2part) {
    int tid = threadIdx.x, bid = blockIdx.x;
    if (bid < 250) {
        __shared__ __align__(16) int ys[BB];    // 8 KB
        __shared__ int mlist[BB];               // 8 KB (pathological-y safe)
        __shared__ float sacc[4 * DD];          // 1 KB, per-class sums
        __shared__ float part[4][DD];           // 1 KB
        __shared__ int cnts[4];
        __shared__ int mcnt;

        // load y via int4 (512 int4 total), zero LDS accumulators
        const int4* y4 = reinterpret_cast<const int4*>(y);
        int4* ys4 = reinterpret_cast<int4*>(ys);
        ys4[tid] = y4[tid];
        ys4[tid + 256] = y4[tid + 256];
        sacc[tid] = 0.f;                        // 256 == 4*DD exactly
        if (tid < 4) cnts[tid] = 0;
        if (tid == 0) mcnt = 0;
        __syncthreads();

        // scan: compact matches (b, class-local cl) into mlist
        int cbase = bid * 4;
        #pragma unroll
        for (int i = 0; i < BB / 256; ++i) {
            int b = tid + i * 256;
            int cl = ys[b] - cbase;
            if ((unsigned)cl < 4u) {
                atomicAdd(&cnts[cl], 1);
                int p = atomicAdd(&mcnt, 1);    // ~8 LDS atomics per block
                mlist[p] = b * 4 + cl;
            }
        }
        __syncthreads();

        // wave-parallel gather: 4 entries per round (wave w -> entry j0+w),
        // each wave does one coalesced 256B row load; accumulate via LDS atomics.
        int n = mcnt;
        int w = tid >> 6, d = tid & 63;
        for (int j0 = 0; j0 < n; j0 += 4) {
            int j = j0 + w;
            if (j < n) {
                int e = mlist[j];
                float v = z[(size_t)(e >> 2) * DD + d];
                atomicAdd(&sacc[(e & 3) * DD + d], v);
            }
        }
        __syncthreads();

        // finalize: thread (cl=w, d)
        float s  = sacc[w * DD + d];
        float nn = (float)cnts[w];
        float ce = nn + EPS_STATS;
        float inv = 1.0f / ce;
        float m = s * inv;
        int c = cbase + w;
        mean[(size_t)c * DD + d] = m;           // contiguous 1KB per block
        if (d == 0) logpr[c] = logf(ce / TSUM);
        // class corr at dim d: s^2 (n+2e)/(n+e)^2  (== 2ms - n m^2 exactly)
        part[w][d] = s * s * (nn + 2.f * EPS_STATS) * inv * inv;
        __syncthreads();
        if (tid < DD)
            corrPart[bid * DD + tid] =
                part[0][tid] + part[1][tid] + part[2][tid] + part[3][tid];
    } else {
        __shared__ float p2[4][DD];
        int tb = bid - 250;                     // 0..63
        int d = tid & 63, grp = tid >> 6;
        int r0 = tb * 32 + grp * 8;
        float a = 0.f;
        #pragma unroll
        for (int r = 0; r < 8; ++r) {
            float v = z[(size_t)(r0 + r) * DD + d];  // coalesced
            a = fmaf(v, v, a);
        }
        p2[grp][d] = a;
        __syncthreads();
        if (tid < DD)
            T2part[tb * DD + tid] =
                p2[0][tid] + p2[1][tid] + p2[2][tid] + p2[3][tid];
    }
}

// --- K_B: fused precision + MFMA scoring. Grid (32,16); block = 64b x 64c tile.
// out[b][c] = (logpr[c] - 0.5*K_c) + dot(w_c, z_b) - 0.5*S_b,  w = p*mean.
__global__ void __launch_bounds__(256)
k_score_mfma(const float* __restrict__ z, const float* __restrict__ mean,
             const float* __restrict__ logpr, const float* __restrict__ corrPart,
             const float* __restrict__ T2part, float* __restrict__ out) {
    __shared__ __align__(16) float red[16][DD];
    __shared__ float ps_s[DD];
    int tid = threadIdx.x;

    // precision: per-block redundant reduce of partials, float4-vectorized.
    // thread = (row-group r0, 4-col chunk c4); 16 threads cover one 256B row.
    {
        int r0 = tid >> 4;            // 0..15
        int c4 = (tid & 15) * 4;      // 0,4,..,60
        float ax = 0.f, ay = 0.f, az = 0.f, aw = 0.f;
        for (int t = r0; t < 64; t += 16) {
            float4 v = *reinterpret_cast<const float4*>(&T2part[t * DD + c4]);
            ax += v.x; ay += v.y; az += v.z; aw += v.w;
        }
        for (int p = r0; p < 250; p += 16) {
            float4 v = *reinterpret_cast<const float4*>(&corrPart[p * DD + c4]);
            ax -= v.x; ay -= v.y; az -= v.z; aw -= v.w;
        }
        float4 a4 = {ax, ay, az, aw};
        *reinterpret_cast<float4*>(&red[r0][c4]) = a4;
    }
    __syncthreads();
    if (tid < DD) {
        float acc = 0.f;
        #pragma unroll
        for (int g = 0; g < 16; ++g) acc += red[g][tid];
        float pooled = acc / TSUM + EPS_STATS;
        ps_s[tid] = 1.0f / fmaxf(pooled, EPS_PREC);
    }
    __syncthreads();

    int wv = tid >> 6, l = tid & 63;
    int lr = l & 15, lg = l >> 4;          // lane-row (M/N idx), k-group
    int b0 = blockIdx.x * 64 + wv * 16;    // wave's 16 output rows
    int c0 = blockIdx.y * 64;              // block's 64 classes

    // per-lane precision slice for k = lg*8+j (kstep0) and +32 (kstep1)
    float ps0[8], ps1[8];
    #pragma unroll
    for (int j = 0; j < 8; ++j) { ps0[j] = ps_s[lg * 8 + j]; ps1[j] = ps_s[32 + lg * 8 + j]; }

    // A fragments: z row (b0+lr) via float4; also S_b partial
    const float* zrow = z + (size_t)(b0 + lr) * DD;
    float4 z00 = *reinterpret_cast<const float4*>(zrow + lg * 8);
    float4 z01 = *reinterpret_cast<const float4*>(zrow + lg * 8 + 4);
    float4 z10 = *reinterpret_cast<const float4*>(zrow + 32 + lg * 8);
    float4 z11 = *reinterpret_cast<const float4*>(zrow + 32 + lg * 8 + 4);
    float zf0[8] = {z00.x, z00.y, z00.z, z00.w, z01.x, z01.y, z01.z, z01.w};
    float zf1[8] = {z10.x, z10.y, z10.z, z10.w, z11.x, z11.y, z11.z, z11.w};
    bf8 a0, a1;
    float sbp = 0.f;
    #pragma unroll
    for (int j = 0; j < 8; ++j) {
        a0[j] = (short)f2bf(zf0[j]);
        a1[j] = (short)f2bf(zf1[j]);
        sbp = fmaf(ps0[j] * zf0[j], zf0[j], sbp);
        sbp = fmaf(ps1[j] * zf1[j], zf1[j], sbp);
    }
    sbp += __shfl_xor(sbp, 16);
    sbp += __shfl_xor(sbp, 32);            // lane holds S for row b0+lr

    f32x4 acc[4];
    float cstv[4];
    #pragma unroll
    for (int ct = 0; ct < 4; ++ct) {
        int c = c0 + ct * 16 + lr;
        int cm = (c < CC) ? c : (CC - 1);
        const float* mrow = mean + (size_t)cm * DD;
        float4 m00 = *reinterpret_cast<const float4*>(mrow + lg * 8);
        float4 m01 = *reinterpret_cast<const float4*>(mrow + lg * 8 + 4);
        float4 m10 = *reinterpret_cast<const float4*>(mrow + 32 + lg * 8);
        float4 m11 = *reinterpret_cast<const float4*>(mrow + 32 + lg * 8 + 4);
        float mf0[8] = {m00.x, m00.y, m00.z, m00.w, m01.x, m01.y, m01.z, m01.w};
        float mf1[8] = {m10.x, m10.y, m10.z, m10.w, m11.x, m11.y, m11.z, m11.w};
        bf8 w0, w1;
        float kc = 0.f;
        #pragma unroll
        for (int j = 0; j < 8; ++j) {
            float wf0 = ps0[j] * mf0[j], wf1 = ps1[j] * mf1[j];
            w0[j] = (short)f2bf(wf0);
            w1[j] = (short)f2bf(wf1);
            kc = fmaf(wf0, mf0[j], kc);
            kc = fmaf(wf1, mf1[j], kc);
        }
        kc += __shfl_xor(kc, 16);
        kc += __shfl_xor(kc, 32);          // K_c for class cm
        cstv[ct] = fmaf(-0.5f, kc, logpr[cm]);
        f32x4 a = {0.f, 0.f, 0.f, 0.f};
        a = __builtin_amdgcn_mfma_f32_16x16x32_bf16(a0, w0, a, 0, 0, 0);
        a = __builtin_amdgcn_mfma_f32_16x16x32_bf16(a1, w1, a, 0, 0, 0);
        acc[ct] = a;
    }

    // epilogue: D row = lg*4+r, col = lr
    float sbv[4];
    #pragma unroll
    for (int r = 0; r < 4; ++r) sbv[r] = __shfl(sbp, lg * 4 + r);
    #pragma unroll
    for (int ct = 0; ct < 4; ++ct) {
        int c = c0 + ct * 16 + lr;
        if (c < CC) {
            #pragma unroll
            for (int r = 0; r < 4; ++r) {
                int b = b0 + lg * 4 + r;
                out[(size_t)b * CC + c] = acc[ct][r] + cstv[ct] - 0.5f * sbv[r];
            }
        }
    }
}

extern "C" void kernel_launch(void* const* d_in, const int* in_sizes, int n_in,
                              void* d_out, int out_size, void* d_ws, size_t ws_size,
                              hipStream_t stream) {
    const float* z = (const float*)d_in[0];
    const int*   y = (const int*)d_in[1];
    float* out = (float*)d_out;

    // ws: all arrays written every call before read; no zeroing needed.
    float* mean     = (float*)d_ws;            // 64000 (class-major [c][d])
    float* logpr    = mean + DD * CC;          // 1000
    float* corrPart = logpr + CC;              // 250*64 = 16000
    float* T2part   = corrPart + 250 * DD;     // 64*64  =  4096

    k_stats<<<314, 256, 0, stream>>>(z, y, mean, logpr, corrPart, T2part);
    dim3 grid(BB / 64, (CC + 63) / 64);        // 32 x 16
    k_score_mfma<<<grid, 256, 0, stream>>>(z, mean, logpr, corrPart, T2part, out);
}

// Round 9
// 21.064 us; speedup vs baseline: 9.7439x; 1.0978x over previous
//
#include <hip/hip_runtime.h>
#include <hip/hip_bf16.h>
#include <math.h>

#define BB 2048
#define CC 1000
#define DD 64
#define NCB 125            // class blocks, 8 classes each
#define NTB 16             // T2 blocks, 128 rows each
constexpr float EPS_STATS = 1e-5f;
constexpr float EPS_PREC  = 1e-6f;
constexpr float TSUM = (float)BB + (float)CC * EPS_STATS;  // counts.sum()

typedef __attribute__((ext_vector_type(8))) short bf8;     // 8 bf16 (4 VGPR)
typedef __attribute__((ext_vector_type(4))) float f32x4;   // MFMA acc

__device__ inline unsigned short f2bf(float f) {           // RNE f32->bf16
    __hip_bfloat16 h = __float2bfloat16(f);
    return *reinterpret_cast<unsigned short*>(&h);
}

// --- K_A: stats. Blocks 0..124: 8 classes each -> mean, logpr, corrPart[bid].
//   scan y (LDS) -> compact match list -> float4 wave gather (16 entries/round,
//   LDS float atomics) -> finalize.
// Blocks 125..140: T2part[tb][d] = partial sum of z^2 over 128 rows.
__global__ void __launch_bounds__(256)
k_stats(const float* __restrict__ z, const int* __restrict__ y,
        float* __restrict__ mean, float* __restrict__ logpr,
        float* __restrict__ corrPart, float* __restrict__ T2part) {
    int tid = threadIdx.x, bid = blockIdx.x;
    if (bid < NCB) {
        __shared__ __align__(16) int ys[BB];    // 8 KB
        __shared__ int mlist[BB];               // 8 KB (pathological-y safe)
        __shared__ float sacc[8 * DD];          // 2 KB per-class sums
        __shared__ float corrv[8 * DD];         // 2 KB
        __shared__ int cnts[8];
        __shared__ int mcnt;

        const int4* y4 = reinterpret_cast<const int4*>(y);
        int4* ys4 = reinterpret_cast<int4*>(ys);
        ys4[tid] = y4[tid];
        ys4[tid + 256] = y4[tid + 256];
        sacc[tid] = 0.f; sacc[tid + 256] = 0.f;
        if (tid < 8) cnts[tid] = 0;
        if (tid == 0) mcnt = 0;
        __syncthreads();

        // scan: compact matches (b, class-local cl) into mlist
        int cbase = bid * 8;
        #pragma unroll
        for (int i = 0; i < BB / 256; ++i) {
            int b = tid + i * 256;
            int cl = ys[b] - cbase;
            if ((unsigned)cl < 8u) {
                atomicAdd(&cnts[cl], 1);
                int p = atomicAdd(&mcnt, 1);    // ~16 LDS atomics per block
                mlist[p] = b * 8 + cl;
            }
        }
        __syncthreads();

        // gather: 16 entries/round; lane-group (lane>>4) picks entry,
        // (lane&15)*4 picks dims -> one float4 per lane, 256B row per group.
        int n = mcnt;
        int w = tid >> 6, lane = tid & 63;
        int eg = w * 4 + (lane >> 4);           // entry slot 0..15
        int d4 = (lane & 15) * 4;
        for (int j0 = 0; j0 < n; j0 += 16) {
            int j = j0 + eg;
            if (j < n) {
                int e = mlist[j];
                float4 v = *reinterpret_cast<const float4*>(
                    &z[(size_t)(e >> 3) * DD + d4]);
                float* sa = &sacc[(e & 7) * DD + d4];
                atomicAdd(sa + 0, v.x);
                atomicAdd(sa + 1, v.y);
                atomicAdd(sa + 2, v.z);
                atomicAdd(sa + 3, v.w);
            }
        }
        __syncthreads();

        // finalize: 512 (cl,d) slots over 2 iterations
        #pragma unroll
        for (int i = 0; i < 2; ++i) {
            int idx = tid + i * 256;
            int cl = idx >> 6, d = idx & 63;
            float s  = sacc[idx];
            float nn = (float)cnts[cl];
            float ce = nn + EPS_STATS;
            float inv = 1.0f / ce;
            int c = cbase + cl;
            mean[(size_t)c * DD + d] = s * inv;      // contiguous 2KB per block
            if (d == 0) logpr[c] = logf(ce / TSUM);
            // class corr at dim d: s^2 (n+2e)/(n+e)^2  (== 2ms - n m^2 exactly)
            corrv[idx] = s * s * (nn + 2.f * EPS_STATS) * inv * inv;
        }
        __syncthreads();
        if (tid < DD) {
            float a = 0.f;
            #pragma unroll
            for (int cl = 0; cl < 8; ++cl) a += corrv[cl * DD + tid];
            corrPart[bid * DD + tid] = a;
        }
    } else {
        __shared__ float p2[4][DD];
        int tb = bid - NCB;                     // 0..15
        int d = tid & 63, grp = tid >> 6;
        int r0 = tb * 128 + grp * 32;
        float a = 0.f;
        #pragma unroll 8
        for (int r = 0; r < 32; ++r) {
            float v = z[(size_t)(r0 + r) * DD + d];  // coalesced row reads
            a = fmaf(v, v, a);
        }
        p2[grp][d] = a;
        __syncthreads();
        if (tid < DD)
            T2part[tb * DD + tid] =
                p2[0][tid] + p2[1][tid] + p2[2][tid] + p2[3][tid];
    }
}

// --- K_B: fused precision + MFMA scoring. Grid (32,16); block = 64b x 64c tile.
// out[b][c] = (logpr[c] - 0.5*K_c) + dot(w_c, z_b) - 0.5*S_b,  w = p*mean.
__global__ void __launch_bounds__(256)
k_score_mfma(const float* __restrict__ z, const float* __restrict__ mean,
             const float* __restrict__ logpr, const float* __restrict__ corrPart,
             const float* __restrict__ T2part, float* __restrict__ out) {
    __shared__ __align__(16) float red[16][DD];
    __shared__ float ps_s[DD];
    int tid = threadIdx.x;

    // precision: reduce 141 partial rows (16 T2 + 125 corr), float4-vectorized.
    {
        int r0 = tid >> 4;            // 0..15
        int c4 = (tid & 15) * 4;      // 0,4,..,60
        float4 t = *reinterpret_cast<const float4*>(&T2part[r0 * DD + c4]);
        float ax = t.x, ay = t.y, az = t.z, aw = t.w;
        for (int p = r0; p < NCB; p += 16) {
            float4 v = *reinterpret_cast<const float4*>(&corrPart[p * DD + c4]);
            ax -= v.x; ay -= v.y; az -= v.z; aw -= v.w;
        }
        float4 a4 = {ax, ay, az, aw};
        *reinterpret_cast<float4*>(&red[r0][c4]) = a4;
    }
    __syncthreads();
    if (tid < DD) {
        float acc = 0.f;
        #pragma unroll
        for (int g = 0; g < 16; ++g) acc += red[g][tid];
        float pooled = acc / TSUM + EPS_STATS;
        ps_s[tid] = 1.0f / fmaxf(pooled, EPS_PREC);
    }
    __syncthreads();

    int wv = tid >> 6, l = tid & 63;
    int lr = l & 15, lg = l >> 4;          // lane-row (M/N idx), k-group
    int b0 = blockIdx.x * 64 + wv * 16;    // wave's 16 output rows
    int c0 = blockIdx.y * 64;              // block's 64 classes

    float ps0[8], ps1[8];
    #pragma unroll
    for (int j = 0; j < 8; ++j) { ps0[j] = ps_s[lg * 8 + j]; ps1[j] = ps_s[32 + lg * 8 + j]; }

    // A fragments: z row (b0+lr) via float4; also S_b partial
    const float* zrow = z + (size_t)(b0 + lr) * DD;
    float4 z00 = *reinterpret_cast<const float4*>(zrow + lg * 8);
    float4 z01 = *reinterpret_cast<const float4*>(zrow + lg * 8 + 4);
    float4 z10 = *reinterpret_cast<const float4*>(zrow + 32 + lg * 8);
    float4 z11 = *reinterpret_cast<const float4*>(zrow + 32 + lg * 8 + 4);
    float zf0[8] = {z00.x, z00.y, z00.z, z00.w, z01.x, z01.y, z01.z, z01.w};
    float zf1[8] = {z10.x, z10.y, z10.z, z10.w, z11.x, z11.y, z11.z, z11.w};
    bf8 a0, a1;
    float sbp = 0.f;
    #pragma unroll
    for (int j = 0; j < 8; ++j) {
        a0[j] = (short)f2bf(zf0[j]);
        a1[j] = (short)f2bf(zf1[j]);
        sbp = fmaf(ps0[j] * zf0[j], zf0[j], sbp);
        sbp = fmaf(ps1[j] * zf1[j], zf1[j], sbp);
    }
    sbp += __shfl_xor(sbp, 16);
    sbp += __shfl_xor(sbp, 32);            // lane holds S for row b0+lr

    f32x4 acc[4];
    float cstv[4];
    #pragma unroll
    for (int ct = 0; ct < 4; ++ct) {
        int c = c0 + ct * 16 + lr;
        int cm = (c < CC) ? c : (CC - 1);
        const float* mrow = mean + (size_t)cm * DD;
        float4 m00 = *reinterpret_cast<const float4*>(mrow + lg * 8);
        float4 m01 = *reinterpret_cast<const float4*>(mrow + lg * 8 + 4);
        float4 m10 = *reinterpret_cast<const float4*>(mrow + 32 + lg * 8);
        float4 m11 = *reinterpret_cast<const float4*>(mrow + 32 + lg * 8 + 4);
        float mf0[8] = {m00.x, m00.y, m00.z, m00.w, m01.x, m01.y, m01.z, m01.w};
        float mf1[8] = {m10.x, m10.y, m10.z, m10.w, m11.x, m11.y, m11.z, m11.w};
        bf8 w0, w1;
        float kc = 0.f;
        #pragma unroll
        for (int j = 0; j < 8; ++j) {
            float wf0 = ps0[j] * mf0[j], wf1 = ps1[j] * mf1[j];
            w0[j] = (short)f2bf(wf0);
            w1[j] = (short)f2bf(wf1);
            kc = fmaf(wf0, mf0[j], kc);
            kc = fmaf(wf1, mf1[j], kc);
        }
        kc += __shfl_xor(kc, 16);
        kc += __shfl_xor(kc, 32);          // K_c for class cm
        cstv[ct] = fmaf(-0.5f, kc, logpr[cm]);
        f32x4 a = {0.f, 0.f, 0.f, 0.f};
        a = __builtin_amdgcn_mfma_f32_16x16x32_bf16(a0, w0, a, 0, 0, 0);
        a = __builtin_amdgcn_mfma_f32_16x16x32_bf16(a1, w1, a, 0, 0, 0);
        acc[ct] = a;
    }

    // epilogue: D row = lg*4+r, col = lr
    float sbv[4];
    #pragma unroll
    for (int r = 0; r < 4; ++r) sbv[r] = __shfl(sbp, lg * 4 + r);
    #pragma unroll
    for (int ct = 0; ct < 4; ++ct) {
        int c = c0 + ct * 16 + lr;
        if (c < CC) {
            #pragma unroll
            for (int r = 0; r < 4; ++r) {
                int b = b0 + lg * 4 + r;
                out[(size_t)b * CC + c] = acc[ct][r] + cstv[ct] - 0.5f * sbv[r];
            }
        }
    }
}

extern "C" void kernel_launch(void* const* d_in, const int* in_sizes, int n_in,
                              void* d_out, int out_size, void* d_ws, size_t ws_size,
                              hipStream_t stream) {
    const float* z = (const float*)d_in[0];
    const int*   y = (const int*)d_in[1];
    float* out = (float*)d_out;

    // ws: all arrays written every call before read; no zeroing needed.
    float* mean     = (float*)d_ws;            // 64000 (class-major [c][d])
    float* logpr    = mean + DD * CC;          // 1000
    float* corrPart = logpr + CC;              // 125*64 = 8000
    float* T2part   = corrPart + NCB * DD;     // 16*64  = 1024

    k_stats<<<NCB + NTB, 256, 0, stream>>>(z, y, mean, logpr, corrPart, T2part);
    dim3 grid(BB / 64, (CC + 63) / 64);        // 32 x 16
    k_score_mfma<<<grid, 256, 0, stream>>>(z, mean, logpr, corrPart, T2part, out);
}